// Round 5
// baseline (1906.119 us; speedup 1.0000x reference)
//
#include <hip/hip_runtime.h>
#include <cstdint>

#define B_SZ  1024
#define S_LEN 200
#define H_DIM 256

typedef short s16x8 __attribute__((ext_vector_type(8)));
typedef short s16x4 __attribute__((ext_vector_type(4)));
typedef float f32x4 __attribute__((ext_vector_type(4)));
typedef int   i32x4 __attribute__((ext_vector_type(4)));

__device__ __forceinline__ short f2bf(float f){
  uint32_t u = __float_as_uint(f);
  u += 0x7FFFu + ((u >> 16) & 1u);   // RNE
  return (short)(u >> 16);
}
__device__ __forceinline__ short f2h(float f){
  union { _Float16 h; short s; } u; u.h = (_Float16)f; return u.s;
}
__device__ __forceinline__ float h2f(short s){
  union { short s; _Float16 h; } u; u.s = s; return (float)u.h;
}
__device__ __forceinline__ float sigm(float x){
  return __fdividef(1.f, 1.f + __expf(-x));
}
__device__ __forceinline__ float tanh_f(float x){
  return 1.f - __fdividef(2.f, __expf(2.f*x) + 1.f);
}

// ---- prep: fp32 -> bf16 weights, split into x-part (wx) and h-part ------
__global__ __launch_bounds__(256) void prep_kernel(
    const float* __restrict__ Wr, const float* __restrict__ Wz,
    const float* __restrict__ Wn, const float* __restrict__ W1,
    short* __restrict__ wx, short* __restrict__ wrzh,
    short* __restrict__ wnh, short* __restrict__ w1b){
  const int NWX=196608, NRZ=131072, NN=65536;
  int i = blockIdx.x*256 + threadIdx.x;
  if(i < NWX){
    int o=i>>8, k=i&255;
    float v = (o<256)? Wr[o*512+k] : (o<512)? Wz[(o-256)*512+k] : Wn[(o-512)*512+k];
    wx[i]=f2bf(v);
  } else if(i < NWX+NRZ){
    int j=i-NWX; int o=j>>8, k=j&255;
    float v=(o<256)? Wr[o*512+256+k] : Wz[(o-256)*512+256+k];
    wrzh[j]=f2bf(v);
  } else if(i < NWX+NRZ+NN){
    int j=i-NWX-NRZ; int o=j>>8, k=j&255;
    wnh[j]=f2bf(Wn[o*512+256+k]);
  } else {
    int j=i-NWX-NRZ-NN;
    w1b[j]=f2bf(W1[j]);
  }
}

// ---- attention scores: relu(combined @ W1^T + b1) @ W2 ------------------
__global__ __launch_bounds__(256) void scores_kernel(
    const float* __restrict__ hs, const float* __restrict__ tgt,
    const short* __restrict__ w1, const float* __restrict__ b1,
    const float* __restrict__ w2, float* __restrict__ scores){
  const int tid = threadIdx.x;
  const int lane = tid & 63;
  const int wv  = tid >> 6;
  const int l15 = lane & 15;
  const int q   = lane >> 4;
  const int gw  = blockIdx.x * 4 + wv;    // 0..3199
  float b1v[8], w2v[8];
  #pragma unroll
  for(int nt=0;nt<8;nt++){ b1v[nt]=b1[nt*16+l15]; w2v[nt]=w2[nt*16+l15]; }
  const short* w1p = w1 + (size_t)l15*512 + q*8;
  for(int it=0; it<2; it++){
    int mt0 = gw + it*3200;               // 0..6399
    int mt1 = mt0 + 6400;                 // 6400..12799
    int m0  = mt0*16 + l15;
    int m1  = mt1*16 + l15;
    int bA  = m0 / S_LEN, sA = m0 - bA*S_LEN;
    int bB  = m1 / S_LEN, sB = m1 - bB*S_LEN;
    const float* arowA = hs  + ((size_t)bA*S_LEN + sA)*H_DIM;
    const float* trowA = tgt + (size_t)bA*H_DIM;
    const float* arowB = hs  + ((size_t)bB*S_LEN + sB)*H_DIM;
    const float* trowB = tgt + (size_t)bB*H_DIM;
    f32x4 acc[2][8];
    #pragma unroll
    for(int u=0;u<2;u++)
      #pragma unroll
      for(int nt=0;nt<8;nt++) acc[u][nt] = (f32x4){0.f,0.f,0.f,0.f};
    for(int kt=0;kt<16;kt++){
      int k0 = kt*32 + q*8;
      const float* srcA = (k0 < H_DIM) ? (arowA + k0) : (trowA + (k0 - H_DIM));
      const float* srcB = (k0 < H_DIM) ? (arowB + k0) : (trowB + (k0 - H_DIM));
      float4 a0 = *(const float4*)(srcA);
      float4 a1 = *(const float4*)(srcA+4);
      float4 c0 = *(const float4*)(srcB);
      float4 c1 = *(const float4*)(srcB+4);
      s16x8 aA, aB;
      aA[0]=f2bf(a0.x); aA[1]=f2bf(a0.y); aA[2]=f2bf(a0.z); aA[3]=f2bf(a0.w);
      aA[4]=f2bf(a1.x); aA[5]=f2bf(a1.y); aA[6]=f2bf(a1.z); aA[7]=f2bf(a1.w);
      aB[0]=f2bf(c0.x); aB[1]=f2bf(c0.y); aB[2]=f2bf(c0.z); aB[3]=f2bf(c0.w);
      aB[4]=f2bf(c1.x); aB[5]=f2bf(c1.y); aB[6]=f2bf(c1.z); aB[7]=f2bf(c1.w);
      #pragma unroll
      for(int nt=0;nt<8;nt++){
        s16x8 bf = *(const s16x8*)(w1p + (size_t)nt*16*512 + kt*32);
        acc[0][nt] = __builtin_amdgcn_mfma_f32_16x16x32_bf16(aA, bf, acc[0][nt], 0, 0, 0);
        acc[1][nt] = __builtin_amdgcn_mfma_f32_16x16x32_bf16(aB, bf, acc[1][nt], 0, 0, 0);
      }
    }
    #pragma unroll
    for(int u=0;u<2;u++){
      float sr0=0.f, sr1=0.f, sr2=0.f, sr3=0.f;
      #pragma unroll
      for(int nt=0;nt<8;nt++){
        f32x4 h4 = acc[u][nt];
        sr0 += fmaxf(h4[0]+b1v[nt],0.f)*w2v[nt];
        sr1 += fmaxf(h4[1]+b1v[nt],0.f)*w2v[nt];
        sr2 += fmaxf(h4[2]+b1v[nt],0.f)*w2v[nt];
        sr3 += fmaxf(h4[3]+b1v[nt],0.f)*w2v[nt];
      }
      #pragma unroll
      for(int mask=1; mask<16; mask<<=1){
        sr0 += __shfl_xor(sr0, mask, 64);
        sr1 += __shfl_xor(sr1, mask, 64);
        sr2 += __shfl_xor(sr2, mask, 64);
        sr3 += __shfl_xor(sr3, mask, 64);
      }
      if(l15 < 4){
        float outv = (l15==0)?sr0:(l15==1)?sr1:(l15==2)?sr2:sr3;
        int mt = (u==0)?mt0:mt1;
        scores[(size_t)mt*16 + q*4 + l15] = outv;
      }
    }
  }
}

// ---- masked softmax over S per batch row --------------------------------
__global__ __launch_bounds__(256) void softmax_kernel(
    const float* __restrict__ scores, const int* __restrict__ lengths,
    float* __restrict__ att){
  const int b = blockIdx.x;
  const int s = threadIdx.x;
  const int lane = s & 63, wv = s >> 6;
  __shared__ float red[4];
  __shared__ float red2[4];
  float sc = -1e9f;
  if(s < S_LEN){
    float v = scores[(size_t)b*S_LEN + s];
    sc = (s < lengths[b]) ? v : -1e9f;
  }
  float mx = (s < S_LEN) ? sc : -INFINITY;
  #pragma unroll
  for(int mask=1; mask<64; mask<<=1) mx = fmaxf(mx, __shfl_xor(mx, mask, 64));
  if(lane==0) red[wv] = mx;
  __syncthreads();
  mx = fmaxf(fmaxf(red[0],red[1]), fmaxf(red[2],red[3]));
  float e = (s < S_LEN) ? expf(sc - mx) : 0.f;
  float sum = e;
  #pragma unroll
  for(int mask=1; mask<64; mask<<=1) sum += __shfl_xor(sum, mask, 64);
  if(lane==0) red2[wv] = sum;
  __syncthreads();
  sum = red2[0]+red2[1]+red2[2]+red2[3];
  if(s < S_LEN) att[(size_t)b*S_LEN + s] = e / sum;
}

// ---- x-projection v2: interleaved {xr,xz,xn,pad} f16x4 per (row,col) ----
// Chunk (g,c) = 32 rows x 256 cols x 8 B = 65536 B contiguous at
// xpg + (g*100+c)*65536; row-in-chunk = tl*16 + batch-lane. Each lane's
// store is 8 B; 16 lanes (l15) cover 128 B contiguous -> good coalescing
// (vs the old layout's 384 scalar 2-B stores per wave).
__global__ __launch_bounds__(256) void xproj2_kernel(
    const float* __restrict__ hs, const short* __restrict__ wx,
    const float* __restrict__ br, const float* __restrict__ bz,
    const float* __restrict__ bn, short* __restrict__ xpg){
  const int tid = threadIdx.x;
  const int lane = tid & 63;
  const int wv = tid >> 6;
  const int l15 = lane & 15;
  const int q = lane >> 4;
  const int wid = blockIdx.x*4 + wv;    // 0..6399
  const int g = wid / 100;
  const int c = wid - g*100;
  // A fragments: rows b = g*16 + l15, timesteps s = c*2 + u
  s16x8 a[2][8];
  #pragma unroll
  for(int u=0;u<2;u++){
    const float* ap = hs + ((size_t)(g*16+l15)*S_LEN + (c*2+u))*H_DIM + q*8;
    #pragma unroll
    for(int kt=0;kt<8;kt++){
      f32x4 p0 = *(const f32x4*)(ap + kt*32);
      f32x4 p1 = *(const f32x4*)(ap + kt*32 + 4);
      s16x8 v;
      v[0]=f2bf(p0[0]); v[1]=f2bf(p0[1]); v[2]=f2bf(p0[2]); v[3]=f2bf(p0[3]);
      v[4]=f2bf(p1[0]); v[5]=f2bf(p1[1]); v[6]=f2bf(p1[2]); v[7]=f2bf(p1[3]);
      a[u][kt]=v;
    }
  }
  char* chunk = (char*)xpg + (size_t)(g*100 + c)*65536;
  const short* wbase = wx + (size_t)l15*256 + q*8;
  for(int ct=0; ct<16; ct++){
    int col = ct*16 + l15;
    f32x4 ar0=(f32x4){0,0,0,0}, ar1=(f32x4){0,0,0,0};
    f32x4 az0=(f32x4){0,0,0,0}, az1=(f32x4){0,0,0,0};
    f32x4 an0=(f32x4){0,0,0,0}, an1=(f32x4){0,0,0,0};
    const short* wr_ = wbase + (size_t)(      ct*16)*256;
    const short* wz_ = wbase + (size_t)(256 + ct*16)*256;
    const short* wn_ = wbase + (size_t)(512 + ct*16)*256;
    #pragma unroll
    for(int kt=0;kt<8;kt++){
      s16x8 br_ = *(const s16x8*)(wr_ + kt*32);
      s16x8 bz_ = *(const s16x8*)(wz_ + kt*32);
      s16x8 bn_ = *(const s16x8*)(wn_ + kt*32);
      ar0 = __builtin_amdgcn_mfma_f32_16x16x32_bf16(a[0][kt],br_,ar0,0,0,0);
      ar1 = __builtin_amdgcn_mfma_f32_16x16x32_bf16(a[1][kt],br_,ar1,0,0,0);
      az0 = __builtin_amdgcn_mfma_f32_16x16x32_bf16(a[0][kt],bz_,az0,0,0,0);
      az1 = __builtin_amdgcn_mfma_f32_16x16x32_bf16(a[1][kt],bz_,az1,0,0,0);
      an0 = __builtin_amdgcn_mfma_f32_16x16x32_bf16(a[0][kt],bn_,an0,0,0,0);
      an1 = __builtin_amdgcn_mfma_f32_16x16x32_bf16(a[1][kt],bn_,an1,0,0,0);
    }
    float brv = br[col], bzv = bz[col], bnv = bn[col];
    #pragma unroll
    for(int reg=0;reg<4;reg++){
      s16x4 p0, p1;
      p0[0]=f2h(ar0[reg]+brv); p0[1]=f2h(az0[reg]+bzv); p0[2]=f2h(an0[reg]+bnv); p0[3]=0;
      p1[0]=f2h(ar1[reg]+brv); p1[1]=f2h(az1[reg]+bzv); p1[2]=f2h(an1[reg]+bnv); p1[3]=0;
      *(s16x4*)(chunk + (size_t)(     q*4+reg)*2048 + (size_t)col*8) = p0;
      *(s16x4*)(chunk + (size_t)(16 + q*4+reg)*2048 + (size_t)col*8) = p1;
    }
  }
}

// ---- slim GRU scan v2: interleaved XP, b64 epi reads --------------------
// 64 blocks x 16 batch rows x 1024 threads (16 waves). Chunk = 2 steps =
// 65536 B, double-buffered; staged as 4 exact 16-KB sweeps (tid*16).
// epi1 does ONE ds_read_b64 per r2 ({xr,xz,xn}); xn carried in regs to
// epi2 (zero XP reads there) — replaces 12 scalar ds_read_u16/lane/step.
__global__ __launch_bounds__(1024) void scan2_kernel(
    const short* __restrict__ xpg, const float* __restrict__ att,
    const short* __restrict__ wrzh, const short* __restrict__ wnh,
    float* __restrict__ out){
  // LDS: XP[2][65536] | comb0 8448 | comb1 8448 | attA 12800 = 160768 B
  __shared__ __align__(16) char smem[160768];
  short* comb0 = (short*)(smem + 131072);
  short* comb1 = (short*)(smem + 139520);
  float* attA  = (float*)(smem + 147968);

  const int tid = threadIdx.x;
  const int lane = tid & 63;
  const int wv  = tid >> 6;         // 0..15
  const int l15 = lane & 15;
  const int q   = lane >> 4;
  const int g   = blockIdx.x;
  const int b0  = g * 16;
  const int cX  = wv*16 + l15;      // this lane's owned column (0..255)

  // register-resident h-part weight fragments (96 regs)
  s16x8 wfr[16], wfn[8];
  #pragma unroll
  for(int kt=0;kt<8;kt++){
    wfr[kt*2+0] = *(const s16x8*)(wrzh + (size_t)(cX      )*256 + kt*32 + q*8);
    wfr[kt*2+1] = *(const s16x8*)(wrzh + (size_t)(256 + cX)*256 + kt*32 + q*8);
    wfn[kt]     = *(const s16x8*)(wnh  + (size_t)(cX      )*256 + kt*32 + q*8);
  }
  float hreg[4];
  #pragma unroll
  for(int r2=0;r2<4;r2++) hreg[r2]=0.f;
  for(int i=tid;i<16*264;i+=1024) comb0[i]=0;
  for(int i=tid;i<16*S_LEN;i+=1024) attA[i]=att[(size_t)b0*S_LEN + i];
  // prologue: stage chunk 0 into buf0 (4 exact 16-KB sweeps)
  {
    const char* gsrc = (const char*)xpg + (size_t)g*100*65536;
    i32x4 t0 = *(const i32x4*)(gsrc +         tid*16);
    i32x4 t1 = *(const i32x4*)(gsrc + 16384 + tid*16);
    i32x4 t2 = *(const i32x4*)(gsrc + 32768 + tid*16);
    i32x4 t3 = *(const i32x4*)(gsrc + 49152 + tid*16);
    *(i32x4*)(smem +         tid*16) = t0;
    *(i32x4*)(smem + 16384 + tid*16) = t1;
    *(i32x4*)(smem + 32768 + tid*16) = t2;
    *(i32x4*)(smem + 49152 + tid*16) = t3;
  }
  __syncthreads();

  int cur = 0;
  for(int c=0;c<100;c++){
    const char* XPc = smem + cur*65536;
    char* nb = smem + (cur^1)*65536;
    const char* gsrc = (const char*)xpg + (size_t)(g*100 + c + 1)*65536;
    const bool pf = (c+1 < 100);
    i32x4 v0, v1, v2, v3;
    if(pf){
      v0 = *(const i32x4*)(gsrc +         tid*16);
      v1 = *(const i32x4*)(gsrc + 16384 + tid*16);
    }
    #pragma unroll
    for(int tl=0;tl<2;tl++){
      const int t = c*2 + tl;
      // GEMM1: h(16x256) @ [Wr_h;Wz_h]^T ; reads comb0; tiles {wv, 16+wv}
      f32x4 accR=(f32x4){0.f,0.f,0.f,0.f}, accZ=(f32x4){0.f,0.f,0.f,0.f};
      #pragma unroll
      for(int kt=0;kt<8;kt++){
        s16x8 a = *(const s16x8*)(comb0 + l15*264 + kt*32+q*8);
        accR=__builtin_amdgcn_mfma_f32_16x16x32_bf16(a,wfr[kt*2+0],accR,0,0,0);
        accZ=__builtin_amdgcn_mfma_f32_16x16x32_bf16(a,wfr[kt*2+1],accZ,0,0,0);
      }
      // epi1: one b64 XP read per r2; r -> comb1; z,xn stay in regs
      float zv[4], xnv[4];
      #pragma unroll
      for(int r2=0;r2<4;r2++){
        int row=q*4+r2;
        s16x4 xp4 = *(const s16x4*)(XPc + (size_t)(tl*16+row)*2048 + (size_t)cX*8);
        float xr = h2f(xp4[0]);
        float xz = h2f(xp4[1]);
        xnv[r2]  = h2f(xp4[2]);
        float rg = sigm(accR[r2]+xr);
        comb1[row*264+cX] = f2bf(rg*hreg[r2]);
        zv[r2] = sigm(accZ[r2]+xz)*attA[row*S_LEN + t];
      }
      __syncthreads();                       // C: comb1 ready, comb0 reads done
      // deferred next-chunk staging (writes target the idle buffer)
      if(pf){
        if(tl==0){
          *(i32x4*)(nb +         tid*16) = v0;
          *(i32x4*)(nb + 16384 + tid*16) = v1;
          v2 = *(const i32x4*)(gsrc + 32768 + tid*16);
          v3 = *(const i32x4*)(gsrc + 49152 + tid*16);
        } else {
          *(i32x4*)(nb + 32768 + tid*16) = v2;
          *(i32x4*)(nb + 49152 + tid*16) = v3;
        }
      }
      // GEMM2: [r*h](16x256) @ Wn_h^T ; reads comb1; tile {wv}
      f32x4 acc2 = (f32x4){0.f,0.f,0.f,0.f};
      #pragma unroll
      for(int kt=0;kt<8;kt++){
        s16x8 a = *(const s16x8*)(comb1 + l15*264 + kt*32+q*8);
        acc2=__builtin_amdgcn_mfma_f32_16x16x32_bf16(a,wfn[kt],acc2,0,0,0);
      }
      // epi2: h update entirely in regs; write comb0 for next step's GEMM1
      #pragma unroll
      for(int r2=0;r2<4;r2++){
        float nv = tanh_f(acc2[r2] + xnv[r2]);
        hreg[r2] = fmaf(zv[r2], nv-hreg[r2], hreg[r2]);
        comb0[(q*4+r2)*264+cX] = f2bf(hreg[r2]);
      }
      __syncthreads();                       // A: comb0(next h) ready
    }
    cur ^= 1;
  }
  #pragma unroll
  for(int r2=0;r2<4;r2++)
    out[(size_t)(b0 + q*4 + r2)*H_DIM + cX] = hreg[r2];
}

// ---- fallback tier (Round-3 verified path, 776-f16 layout) --------------
__global__ __launch_bounds__(256) void xproj_old_kernel(
    const float* __restrict__ hs, const short* __restrict__ wx,
    const float* __restrict__ br, const float* __restrict__ bz,
    const float* __restrict__ bn, short* __restrict__ xpg){
  const int tid = threadIdx.x;
  const int lane = tid & 63;
  const int wv = tid >> 6;
  const int l15 = lane & 15;
  const int q = lane >> 4;
  const int wid = blockIdx.x*4 + wv;
  const int g = wid / 100;
  const int c = wid - g*100;
  s16x8 a[2][8];
  #pragma unroll
  for(int u=0;u<2;u++){
    const float* ap = hs + ((size_t)(g*16+l15)*S_LEN + (c*2+u))*H_DIM + q*8;
    #pragma unroll
    for(int kt=0;kt<8;kt++){
      f32x4 p0 = *(const f32x4*)(ap + kt*32);
      f32x4 p1 = *(const f32x4*)(ap + kt*32 + 4);
      s16x8 v;
      v[0]=f2bf(p0[0]); v[1]=f2bf(p0[1]); v[2]=f2bf(p0[2]); v[3]=f2bf(p0[3]);
      v[4]=f2bf(p1[0]); v[5]=f2bf(p1[1]); v[6]=f2bf(p1[2]); v[7]=f2bf(p1[3]);
      a[u][kt]=v;
    }
  }
  _Float16* xp = (_Float16*)xpg;
  const size_t Rbase = (size_t)g*3200 + (size_t)c*32;
  const short* wbase = wx + (size_t)l15*256 + q*8;
  for(int nt=0;nt<48;nt++){
    const short* wp = wbase + (size_t)nt*16*256;
    f32x4 acc0=(f32x4){0.f,0.f,0.f,0.f}, acc1=(f32x4){0.f,0.f,0.f,0.f};
    #pragma unroll
    for(int kt=0;kt<8;kt++){
      s16x8 bf = *(const s16x8*)(wp + kt*32);
      acc0 = __builtin_amdgcn_mfma_f32_16x16x32_bf16(a[0][kt],bf,acc0,0,0,0);
      acc1 = __builtin_amdgcn_mfma_f32_16x16x32_bf16(a[1][kt],bf,acc1,0,0,0);
    }
    int col = nt*16 + l15;
    const float* bp = (nt<16)? (br+nt*16) : (nt<32)? (bz+(nt-16)*16) : (bn+(nt-32)*16);
    float bv = bp[l15];
    #pragma unroll
    for(int reg=0;reg<4;reg++){
      xp[(Rbase      + q*4 + reg)*776 + col] = (_Float16)(acc0[reg] + bv);
      xp[(Rbase + 16 + q*4 + reg)*776 + col] = (_Float16)(acc1[reg] + bv);
    }
  }
}

__global__ __launch_bounds__(1024) void scan2_old_kernel(
    const short* __restrict__ xpg, const float* __restrict__ att,
    const short* __restrict__ wrzh, const short* __restrict__ wnh,
    float* __restrict__ out){
  __shared__ __align__(16) char smem[129024];
  short* comb0 = (short*)(smem + 99328);
  short* comb1 = (short*)(smem + 107776);
  float* attA  = (float*)(smem + 116224);

  const int tid = threadIdx.x;
  const int lane = tid & 63;
  const int wv  = tid >> 6;
  const int l15 = lane & 15;
  const int q   = lane >> 4;
  const int g   = blockIdx.x;
  const int b0  = g * 16;
  const int cX  = wv*16 + l15;

  s16x8 wfr[16], wfn[8];
  #pragma unroll
  for(int kt=0;kt<8;kt++){
    wfr[kt*2+0] = *(const s16x8*)(wrzh + (size_t)(cX      )*256 + kt*32 + q*8);
    wfr[kt*2+1] = *(const s16x8*)(wrzh + (size_t)(256 + cX)*256 + kt*32 + q*8);
    wfn[kt]     = *(const s16x8*)(wnh  + (size_t)(cX      )*256 + kt*32 + q*8);
  }
  float hreg[4];
  #pragma unroll
  for(int r2=0;r2<4;r2++) hreg[r2]=0.f;
  for(int i=tid;i<16*264;i+=1024) comb0[i]=0;
  for(int i=tid;i<16*S_LEN;i+=1024) attA[i]=att[(size_t)b0*S_LEN + i];
  {
    const char* gsrc = (const char*)xpg + (size_t)g*100*49664;
    i32x4 t0 = *(const i32x4*)(gsrc +         tid*16);
    i32x4 t1 = *(const i32x4*)(gsrc + 16384 + tid*16);
    i32x4 t2 = *(const i32x4*)(gsrc + 32768 + tid*16);
    *(i32x4*)(smem +         tid*16) = t0;
    *(i32x4*)(smem + 16384 + tid*16) = t1;
    *(i32x4*)(smem + 32768 + tid*16) = t2;
    if(tid<32){
      i32x4 t3 = *(const i32x4*)(gsrc + 49152 + tid*16);
      *(i32x4*)(smem + 49152 + tid*16) = t3;
    }
  }
  __syncthreads();

  int cur = 0;
  for(int c=0;c<100;c++){
    const _Float16* XPc = (const _Float16*)(smem + cur*49664);
    char* nb = smem + (cur^1)*49664;
    const char* gsrc = (const char*)xpg + (size_t)(g*100 + c + 1)*49664;
    const bool pf = (c+1 < 100);
    i32x4 v0, v1, v2, v3;
    if(pf){
      v0 = *(const i32x4*)(gsrc +         tid*16);
      v1 = *(const i32x4*)(gsrc + 16384 + tid*16);
    }
    #pragma unroll
    for(int tl=0;tl<2;tl++){
      const int t = c*2 + tl;
      f32x4 accR=(f32x4){0.f,0.f,0.f,0.f}, accZ=(f32x4){0.f,0.f,0.f,0.f};
      #pragma unroll
      for(int kt=0;kt<8;kt++){
        s16x8 a = *(const s16x8*)(comb0 + l15*264 + kt*32+q*8);
        accR=__builtin_amdgcn_mfma_f32_16x16x32_bf16(a,wfr[kt*2+0],accR,0,0,0);
        accZ=__builtin_amdgcn_mfma_f32_16x16x32_bf16(a,wfr[kt*2+1],accZ,0,0,0);
      }
      float zv[4];
      #pragma unroll
      for(int r2=0;r2<4;r2++){
        int row=q*4+r2;
        float xr = (float)XPc[(size_t)(tl*16+row)*776 +       cX];
        float xz = (float)XPc[(size_t)(tl*16+row)*776 + 256 + cX];
        float rg = sigm(accR[r2]+xr);
        comb1[row*264+cX] = f2bf(rg*hreg[r2]);
        zv[r2] = sigm(accZ[r2]+xz)*attA[row*S_LEN + t];
      }
      __syncthreads();
      if(pf){
        if(tl==0){
          *(i32x4*)(nb +         tid*16) = v0;
          *(i32x4*)(nb + 16384 + tid*16) = v1;
          v2 = *(const i32x4*)(gsrc + 32768 + tid*16);
          if(tid<32) v3 = *(const i32x4*)(gsrc + 49152 + tid*16);
        } else {
          *(i32x4*)(nb + 32768 + tid*16) = v2;
          if(tid<32) *(i32x4*)(nb + 49152 + tid*16) = v3;
        }
      }
      f32x4 acc2 = (f32x4){0.f,0.f,0.f,0.f};
      #pragma unroll
      for(int kt=0;kt<8;kt++){
        s16x8 a = *(const s16x8*)(comb1 + l15*264 + kt*32+q*8);
        acc2=__builtin_amdgcn_mfma_f32_16x16x32_bf16(a,wfn[kt],acc2,0,0,0);
      }
      #pragma unroll
      for(int r2=0;r2<4;r2++){
        int row=q*4+r2;
        float xn = (float)XPc[(size_t)(tl*16+row)*776 + 512 + cX];
        float nv = tanh_f(acc2[r2]+xn);
        hreg[r2] = fmaf(zv[r2], nv-hreg[r2], hreg[r2]);
        comb0[row*264+cX] = f2bf(hreg[r2]);
      }
      __syncthreads();
    }
  }
  #pragma unroll
  for(int r2=0;r2<4;r2++)
    out[(size_t)(b0 + q*4 + r2)*H_DIM + cX] = hreg[r2];
}

extern "C" void kernel_launch(void* const* d_in, const int* in_sizes, int n_in,
                              void* d_out, int out_size, void* d_ws, size_t ws_size,
                              hipStream_t stream) {
  const float* hs  = (const float*)d_in[0];
  const float* tgt = (const float*)d_in[1];
  const int*   len = (const int*)d_in[2];
  const float* W1  = (const float*)d_in[3];
  const float* b1  = (const float*)d_in[4];
  const float* W2  = (const float*)d_in[5];
  const float* Wr  = (const float*)d_in[6];
  const float* br  = (const float*)d_in[7];
  const float* Wz  = (const float*)d_in[8];
  const float* bz  = (const float*)d_in[9];
  const float* Wn  = (const float*)d_in[10];
  const float* bn  = (const float*)d_in[11];
  float* out = (float*)d_out;

  const size_t WTS = (size_t)458752*2 + (size_t)819200*2;  // weights + scores/att
  const size_t XPG2_BYTES = (size_t)6400 * 65536;          // 419,430,400
  const size_t XPG1_BYTES = (size_t)204800 * 776 * 2;      // 317,849,600
  if(ws_size >= XPG2_BYTES + WTS){
    // interleaved path: XPg2 | wx | wrzh | wnh | w1b | scores | att
    short* xpgs = (short*)d_ws;
    short* wx   = (short*)((char*)d_ws + XPG2_BYTES);
    short* wrzh = wx + 196608;
    short* wnh  = wrzh + 131072;
    short* w1b  = wnh + 65536;
    float* scores = (float*)(w1b + 65536);
    float* att    = scores + (size_t)B_SZ*S_LEN;
    prep_kernel<<<1792, 256, 0, stream>>>(Wr, Wz, Wn, W1, wx, wrzh, wnh, w1b);
    xproj2_kernel<<<1600, 256, 0, stream>>>(hs, wx, br, bz, bn, xpgs);
    scores_kernel<<<800, 256, 0, stream>>>(hs, tgt, w1b, b1, W2, scores);
    softmax_kernel<<<1024, 256, 0, stream>>>(scores, len, att);
    scan2_kernel<<<64, 1024, 0, stream>>>(xpgs, att, wrzh, wnh, out);
  } else {
    // Round-3 verified fallback: XPg1 | wx | wrzh | wnh | w1b | scores | att
    short* xpgs = (short*)d_ws;
    short* wx   = (short*)((char*)d_ws + XPG1_BYTES);
    short* wrzh = wx + 196608;
    short* wnh  = wrzh + 131072;
    short* w1b  = wnh + 65536;
    float* scores = (float*)(w1b + 65536);
    float* att    = scores + (size_t)B_SZ*S_LEN;
    prep_kernel<<<1792, 256, 0, stream>>>(Wr, Wz, Wn, W1, wx, wrzh, wnh, w1b);
    xproj_old_kernel<<<1600, 256, 0, stream>>>(hs, wx, br, bz, bn, xpgs);
    scores_kernel<<<800, 256, 0, stream>>>(hs, tgt, w1b, b1, W2, scores);
    softmax_kernel<<<1024, 256, 0, stream>>>(scores, len, att);
    scan2_old_kernel<<<64, 1024, 0, stream>>>(xpgs, att, wrzh, wnh, out);
  }
}

// Round 7
// 1613.291 us; speedup vs baseline: 1.1815x; 1.1815x over previous
//
#include <hip/hip_runtime.h>
#include <cstdint>

#define B_SZ  1024
#define S_LEN 200
#define H_DIM 256

typedef short s16x8 __attribute__((ext_vector_type(8)));
typedef float f32x4 __attribute__((ext_vector_type(4)));
typedef int   i32x4 __attribute__((ext_vector_type(4)));

__device__ __forceinline__ short f2bf(float f){
  uint32_t u = __float_as_uint(f);
  u += 0x7FFFu + ((u >> 16) & 1u);   // RNE
  return (short)(u >> 16);
}
__device__ __forceinline__ float sigm(float x){
  return __fdividef(1.f, 1.f + __expf(-x));
}
__device__ __forceinline__ float tanh_f(float x){
  return 1.f - __fdividef(2.f, __expf(2.f*x) + 1.f);
}

// ---- prep: fp32 -> bf16 weights, split into x-part (wx) and h-part ------
__global__ __launch_bounds__(256) void prep_kernel(
    const float* __restrict__ Wr, const float* __restrict__ Wz,
    const float* __restrict__ Wn, const float* __restrict__ W1,
    short* __restrict__ wx, short* __restrict__ wrzh,
    short* __restrict__ wnh, short* __restrict__ w1b){
  const int NWX=196608, NRZ=131072, NN=65536;
  int i = blockIdx.x*256 + threadIdx.x;
  if(i < NWX){
    int o=i>>8, k=i&255;
    float v = (o<256)? Wr[o*512+k] : (o<512)? Wz[(o-256)*512+k] : Wn[(o-512)*512+k];
    wx[i]=f2bf(v);
  } else if(i < NWX+NRZ){
    int j=i-NWX; int o=j>>8, k=j&255;
    float v=(o<256)? Wr[o*512+256+k] : Wz[(o-256)*512+256+k];
    wrzh[j]=f2bf(v);
  } else if(i < NWX+NRZ+NN){
    int j=i-NWX-NRZ; int o=j>>8, k=j&255;
    wnh[j]=f2bf(Wn[o*512+256+k]);
  } else {
    int j=i-NWX-NRZ-NN;
    w1b[j]=f2bf(W1[j]);
  }
}

// ---- attention scores: relu(combined @ W1^T + b1) @ W2 ------------------
__global__ __launch_bounds__(256) void scores_kernel(
    const float* __restrict__ hs, const float* __restrict__ tgt,
    const short* __restrict__ w1, const float* __restrict__ b1,
    const float* __restrict__ w2, float* __restrict__ scores){
  const int tid = threadIdx.x;
  const int lane = tid & 63;
  const int wv  = tid >> 6;
  const int l15 = lane & 15;
  const int q   = lane >> 4;
  const int gw  = blockIdx.x * 4 + wv;    // 0..3199
  float b1v[8], w2v[8];
  #pragma unroll
  for(int nt=0;nt<8;nt++){ b1v[nt]=b1[nt*16+l15]; w2v[nt]=w2[nt*16+l15]; }
  const short* w1p = w1 + (size_t)l15*512 + q*8;
  for(int it=0; it<2; it++){
    int mt0 = gw + it*3200;               // 0..6399
    int mt1 = mt0 + 6400;                 // 6400..12799
    int m0  = mt0*16 + l15;
    int m1  = mt1*16 + l15;
    int bA  = m0 / S_LEN, sA = m0 - bA*S_LEN;
    int bB  = m1 / S_LEN, sB = m1 - bB*S_LEN;
    const float* arowA = hs  + ((size_t)bA*S_LEN + sA)*H_DIM;
    const float* trowA = tgt + (size_t)bA*H_DIM;
    const float* arowB = hs  + ((size_t)bB*S_LEN + sB)*H_DIM;
    const float* trowB = tgt + (size_t)bB*H_DIM;
    f32x4 acc[2][8];
    #pragma unroll
    for(int u=0;u<2;u++)
      #pragma unroll
      for(int nt=0;nt<8;nt++) acc[u][nt] = (f32x4){0.f,0.f,0.f,0.f};
    for(int kt=0;kt<16;kt++){
      int k0 = kt*32 + q*8;
      const float* srcA = (k0 < H_DIM) ? (arowA + k0) : (trowA + (k0 - H_DIM));
      const float* srcB = (k0 < H_DIM) ? (arowB + k0) : (trowB + (k0 - H_DIM));
      float4 a0 = *(const float4*)(srcA);
      float4 a1 = *(const float4*)(srcA+4);
      float4 c0 = *(const float4*)(srcB);
      float4 c1 = *(const float4*)(srcB+4);
      s16x8 aA, aB;
      aA[0]=f2bf(a0.x); aA[1]=f2bf(a0.y); aA[2]=f2bf(a0.z); aA[3]=f2bf(a0.w);
      aA[4]=f2bf(a1.x); aA[5]=f2bf(a1.y); aA[6]=f2bf(a1.z); aA[7]=f2bf(a1.w);
      aB[0]=f2bf(c0.x); aB[1]=f2bf(c0.y); aB[2]=f2bf(c0.z); aB[3]=f2bf(c0.w);
      aB[4]=f2bf(c1.x); aB[5]=f2bf(c1.y); aB[6]=f2bf(c1.z); aB[7]=f2bf(c1.w);
      #pragma unroll
      for(int nt=0;nt<8;nt++){
        s16x8 bf = *(const s16x8*)(w1p + (size_t)nt*16*512 + kt*32);
        acc[0][nt] = __builtin_amdgcn_mfma_f32_16x16x32_bf16(aA, bf, acc[0][nt], 0, 0, 0);
        acc[1][nt] = __builtin_amdgcn_mfma_f32_16x16x32_bf16(aB, bf, acc[1][nt], 0, 0, 0);
      }
    }
    #pragma unroll
    for(int u=0;u<2;u++){
      float sr0=0.f, sr1=0.f, sr2=0.f, sr3=0.f;
      #pragma unroll
      for(int nt=0;nt<8;nt++){
        f32x4 h4 = acc[u][nt];
        sr0 += fmaxf(h4[0]+b1v[nt],0.f)*w2v[nt];
        sr1 += fmaxf(h4[1]+b1v[nt],0.f)*w2v[nt];
        sr2 += fmaxf(h4[2]+b1v[nt],0.f)*w2v[nt];
        sr3 += fmaxf(h4[3]+b1v[nt],0.f)*w2v[nt];
      }
      #pragma unroll
      for(int mask=1; mask<16; mask<<=1){
        sr0 += __shfl_xor(sr0, mask, 64);
        sr1 += __shfl_xor(sr1, mask, 64);
        sr2 += __shfl_xor(sr2, mask, 64);
        sr3 += __shfl_xor(sr3, mask, 64);
      }
      if(l15 < 4){
        float outv = (l15==0)?sr0:(l15==1)?sr1:(l15==2)?sr2:sr3;
        int mt = (u==0)?mt0:mt1;
        scores[(size_t)mt*16 + q*4 + l15] = outv;
      }
    }
  }
}

// ---- masked softmax over S per batch row --------------------------------
__global__ __launch_bounds__(256) void softmax_kernel(
    const float* __restrict__ scores, const int* __restrict__ lengths,
    float* __restrict__ att){
  const int b = blockIdx.x;
  const int s = threadIdx.x;
  const int lane = s & 63, wv = s >> 6;
  __shared__ float red[4];
  __shared__ float red2[4];
  float sc = -1e9f;
  if(s < S_LEN){
    float v = scores[(size_t)b*S_LEN + s];
    sc = (s < lengths[b]) ? v : -1e9f;
  }
  float mx = (s < S_LEN) ? sc : -INFINITY;
  #pragma unroll
  for(int mask=1; mask<64; mask<<=1) mx = fmaxf(mx, __shfl_xor(mx, mask, 64));
  if(lane==0) red[wv] = mx;
  __syncthreads();
  mx = fmaxf(fmaxf(red[0],red[1]), fmaxf(red[2],red[3]));
  float e = (s < S_LEN) ? expf(sc - mx) : 0.f;
  float sum = e;
  #pragma unroll
  for(int mask=1; mask<64; mask<<=1) sum += __shfl_xor(sum, mask, 64);
  if(lane==0) red2[wv] = sum;
  __syncthreads();
  sum = red2[0]+red2[1]+red2[2]+red2[3];
  if(s < S_LEN) att[(size_t)b*S_LEN + s] = e / sum;
}

// ---- x-projection v3: wx LDS-staged per block (kills 2.5 GB of HBM) -----
// 400 blocks x 1024 threads (16 waves); each wave one (g,c) job. Block
// stages wx in 8 double-buffered stages of 48 KB ([6 subtiles][16][256]
// shorts, 16-B chunk index XOR-swizzled by row&7 -> conflict-free staging
// writes AND compute reads). wx HBM traffic: 6400x393KB=2.5GB -> 400x393KB
// =157MB. Output layout: Round-3 planar 776-f16 rows (verified pair with
// scan2).
__global__ __launch_bounds__(1024) void xproj3_kernel(
    const float* __restrict__ hs, const short* __restrict__ wx,
    const float* __restrict__ br, const float* __restrict__ bz,
    const float* __restrict__ bn, short* __restrict__ xpg){
  __shared__ __align__(16) short stg[2][6*16*256];  // 2 x 49152 B
  const int tid = threadIdx.x;
  const int lane = tid & 63;
  const int wv = tid >> 6;
  const int l15 = lane & 15;
  const int q = lane >> 4;
  const int wid = blockIdx.x*16 + wv;    // 0..6399
  const int g = wid / 100;
  const int c = wid - g*100;
  // A fragments: rows b = g*16 + l15, timesteps s = c*2 + u
  s16x8 a[2][8];
  #pragma unroll
  for(int u=0;u<2;u++){
    const float* ap = hs + ((size_t)(g*16+l15)*S_LEN + (c*2+u))*H_DIM + q*8;
    #pragma unroll
    for(int kt=0;kt<8;kt++){
      f32x4 p0 = *(const f32x4*)(ap + kt*32);
      f32x4 p1 = *(const f32x4*)(ap + kt*32 + 4);
      s16x8 v;
      v[0]=f2bf(p0[0]); v[1]=f2bf(p0[1]); v[2]=f2bf(p0[2]); v[3]=f2bf(p0[3]);
      v[4]=f2bf(p1[0]); v[5]=f2bf(p1[1]); v[6]=f2bf(p1[2]); v[7]=f2bf(p1[3]);
      a[u][kt]=v;
    }
  }
  // stage 0: thread w = tid + j*1024 -> (m = w>>10, rr = (w&1023)>>5, kc = w&31)
  // global: wx[(m*256 + s*32 + rr)*256 + kc*8 .. +8)   (i32x4, coalesced)
  // LDS: subtile mt = m*2+(rr>>4), row rr&15, chunk (kc ^ (rr&7))
  i32x4 st[3];
  #pragma unroll
  for(int j=0;j<3;j++){
    int w = tid + j*1024;
    int m = w>>10, rem = w&1023, rr = rem>>5, kc = rem&31;
    st[j] = *(const i32x4*)(wx + ((size_t)(m<<8) + rr)*256 + kc*8);
  }
  #pragma unroll
  for(int j=0;j<3;j++){
    int w = tid + j*1024;
    int m = w>>10, rem = w&1023, rr = rem>>5, kc = rem&31;
    *(i32x4*)(&stg[0][((m*2+(rr>>4))*16 + (rr&15))*256 + (kc^(rr&7))*8]) = st[j];
  }
  __syncthreads();

  const size_t Rbase = (size_t)g*3200 + (size_t)c*32;
  _Float16* xp = (_Float16*)xpg;
  for(int s=0;s<8;s++){
    const short* sb = stg[s&1];
    if(s<7){
      #pragma unroll
      for(int j=0;j<3;j++){
        int w = tid + j*1024;
        int m = w>>10, rem = w&1023, rr = rem>>5, kc = rem&31;
        st[j] = *(const i32x4*)(wx + ((size_t)(m<<8) + (s+1)*32 + rr)*256 + kc*8);
      }
    }
    #pragma unroll
    for(int cc=0;cc<2;cc++){
      int ct = s*2+cc;
      f32x4 ar0=(f32x4){0,0,0,0}, ar1=(f32x4){0,0,0,0};
      f32x4 az0=(f32x4){0,0,0,0}, az1=(f32x4){0,0,0,0};
      f32x4 an0=(f32x4){0,0,0,0}, an1=(f32x4){0,0,0,0};
      #pragma unroll
      for(int kt=0;kt<8;kt++){
        int ch = ((kt*4+q) ^ (l15&7))*8;
        s16x8 br_ = *(const s16x8*)(sb + ((0+cc)*16 + l15)*256 + ch);
        s16x8 bz_ = *(const s16x8*)(sb + ((2+cc)*16 + l15)*256 + ch);
        s16x8 bn_ = *(const s16x8*)(sb + ((4+cc)*16 + l15)*256 + ch);
        ar0 = __builtin_amdgcn_mfma_f32_16x16x32_bf16(a[0][kt],br_,ar0,0,0,0);
        ar1 = __builtin_amdgcn_mfma_f32_16x16x32_bf16(a[1][kt],br_,ar1,0,0,0);
        az0 = __builtin_amdgcn_mfma_f32_16x16x32_bf16(a[0][kt],bz_,az0,0,0,0);
        az1 = __builtin_amdgcn_mfma_f32_16x16x32_bf16(a[1][kt],bz_,az1,0,0,0);
        an0 = __builtin_amdgcn_mfma_f32_16x16x32_bf16(a[0][kt],bn_,an0,0,0,0);
        an1 = __builtin_amdgcn_mfma_f32_16x16x32_bf16(a[1][kt],bn_,an1,0,0,0);
      }
      int col = ct*16 + l15;
      float brv = br[col], bzv = bz[col], bnv = bn[col];
      #pragma unroll
      for(int reg=0;reg<4;reg++){
        size_t r0 = (Rbase      + q*4 + reg)*776;
        size_t r1 = (Rbase + 16 + q*4 + reg)*776;
        xp[r0 +       col] = (_Float16)(ar0[reg] + brv);
        xp[r0 + 256 + col] = (_Float16)(az0[reg] + bzv);
        xp[r0 + 512 + col] = (_Float16)(an0[reg] + bnv);
        xp[r1 +       col] = (_Float16)(ar1[reg] + brv);
        xp[r1 + 256 + col] = (_Float16)(az1[reg] + bzv);
        xp[r1 + 512 + col] = (_Float16)(an1[reg] + bnv);
      }
    }
    __syncthreads();                 // all reads of both buffers done
    if(s<7){
      short* nbuf = stg[(s+1)&1];
      #pragma unroll
      for(int j=0;j<3;j++){
        int w = tid + j*1024;
        int m = w>>10, rem = w&1023, rr = rem>>5, kc = rem&31;
        *(i32x4*)(&nbuf[((m*2+(rr>>4))*16 + (rr&15))*256 + (kc^(rr&7))*8]) = st[j];
      }
      __syncthreads();               // next stage ready
    }
  }
}

// ---- slim GRU scan (Round-3 verified version, 776-f16 planar XP) --------
// 64 blocks x 16 batch rows x 1024 threads (16 waves). Chunk = 2 steps;
// XP double-buffered in LDS (49664 B each), staged via early global loads
// + deferred ds_writes. 4 barriers per chunk.
__global__ __launch_bounds__(1024) void scan2_kernel(
    const short* __restrict__ xpg, const float* __restrict__ att,
    const short* __restrict__ wrzh, const short* __restrict__ wnh,
    float* __restrict__ out){
  // LDS: XP[2][49664] | comb0 8448 | comb1 8448 | attA 12800 = 129024 B
  __shared__ __align__(16) char smem[129024];
  short* comb0 = (short*)(smem + 99328);
  short* comb1 = (short*)(smem + 107776);
  float* attA  = (float*)(smem + 116224);

  const int tid = threadIdx.x;
  const int lane = tid & 63;
  const int wv  = tid >> 6;         // 0..15
  const int l15 = lane & 15;
  const int q   = lane >> 4;
  const int g   = blockIdx.x;
  const int b0  = g * 16;
  const int cX  = wv*16 + l15;      // this lane's owned column (0..255)

  // register-resident h-part weight fragments (96 regs)
  s16x8 wfr[16], wfn[8];
  #pragma unroll
  for(int kt=0;kt<8;kt++){
    wfr[kt*2+0] = *(const s16x8*)(wrzh + (size_t)(cX      )*256 + kt*32 + q*8);
    wfr[kt*2+1] = *(const s16x8*)(wrzh + (size_t)(256 + cX)*256 + kt*32 + q*8);
    wfn[kt]     = *(const s16x8*)(wnh  + (size_t)(cX      )*256 + kt*32 + q*8);
  }
  float hreg[4];
  #pragma unroll
  for(int r2=0;r2<4;r2++) hreg[r2]=0.f;
  for(int i=tid;i<16*264;i+=1024) comb0[i]=0;
  for(int i=tid;i<16*S_LEN;i+=1024) attA[i]=att[(size_t)b0*S_LEN + i];
  // prologue: stage chunk 0 into buf0 (49664 B = 3 full sweeps + 512 tail)
  {
    const char* gsrc = (const char*)xpg + (size_t)g*100*49664;
    i32x4 t0 = *(const i32x4*)(gsrc +         tid*16);
    i32x4 t1 = *(const i32x4*)(gsrc + 16384 + tid*16);
    i32x4 t2 = *(const i32x4*)(gsrc + 32768 + tid*16);
    *(i32x4*)(smem +         tid*16) = t0;
    *(i32x4*)(smem + 16384 + tid*16) = t1;
    *(i32x4*)(smem + 32768 + tid*16) = t2;
    if(tid<32){
      i32x4 t3 = *(const i32x4*)(gsrc + 49152 + tid*16);
      *(i32x4*)(smem + 49152 + tid*16) = t3;
    }
  }
  __syncthreads();

  int cur = 0;
  for(int c=0;c<100;c++){
    const _Float16* XPc = (const _Float16*)(smem + cur*49664);
    char* nb = smem + (cur^1)*49664;
    const char* gsrc = (const char*)xpg + (size_t)(g*100 + c + 1)*49664;
    const bool pf = (c+1 < 100);
    i32x4 v0, v1, v2, v3;
    if(pf){
      v0 = *(const i32x4*)(gsrc +         tid*16);
      v1 = *(const i32x4*)(gsrc + 16384 + tid*16);
    }
    #pragma unroll
    for(int tl=0;tl<2;tl++){
      const int t = c*2 + tl;
      // GEMM1: h(16x256) @ [Wr_h;Wz_h]^T ; reads comb0; tiles {wv, 16+wv}
      f32x4 accR=(f32x4){0.f,0.f,0.f,0.f}, accZ=(f32x4){0.f,0.f,0.f,0.f};
      #pragma unroll
      for(int kt=0;kt<8;kt++){
        s16x8 a = *(const s16x8*)(comb0 + l15*264 + kt*32+q*8);
        accR=__builtin_amdgcn_mfma_f32_16x16x32_bf16(a,wfr[kt*2+0],accR,0,0,0);
        accZ=__builtin_amdgcn_mfma_f32_16x16x32_bf16(a,wfr[kt*2+1],accZ,0,0,0);
      }
      // epi1: r -> comb1 (r*h from h regs), z stays in regs
      float zv[4];
      #pragma unroll
      for(int r2=0;r2<4;r2++){
        int row=q*4+r2;
        float xr = (float)XPc[(size_t)(tl*16+row)*776 +       cX];
        float xz = (float)XPc[(size_t)(tl*16+row)*776 + 256 + cX];
        float rg = sigm(accR[r2]+xr);
        comb1[row*264+cX] = f2bf(rg*hreg[r2]);
        zv[r2] = sigm(accZ[r2]+xz)*attA[row*S_LEN + t];
      }
      __syncthreads();                       // C: comb1 ready, comb0 reads done
      // deferred next-chunk staging (writes target the idle buffer)
      if(pf){
        if(tl==0){
          *(i32x4*)(nb +         tid*16) = v0;
          *(i32x4*)(nb + 16384 + tid*16) = v1;
          v2 = *(const i32x4*)(gsrc + 32768 + tid*16);
          if(tid<32) v3 = *(const i32x4*)(gsrc + 49152 + tid*16);
        } else {
          *(i32x4*)(nb + 32768 + tid*16) = v2;
          if(tid<32) *(i32x4*)(nb + 49152 + tid*16) = v3;
        }
      }
      // GEMM2: [r*h](16x256) @ Wn_h^T ; reads comb1; tile {wv}
      f32x4 acc2 = (f32x4){0.f,0.f,0.f,0.f};
      #pragma unroll
      for(int kt=0;kt<8;kt++){
        s16x8 a = *(const s16x8*)(comb1 + l15*264 + kt*32+q*8);
        acc2=__builtin_amdgcn_mfma_f32_16x16x32_bf16(a,wfn[kt],acc2,0,0,0);
      }
      // epi2: h update entirely in regs; write comb0 for next step's GEMM1
      #pragma unroll
      for(int r2=0;r2<4;r2++){
        int row=q*4+r2;
        float xn = (float)XPc[(size_t)(tl*16+row)*776 + 512 + cX];
        float nv = tanh_f(acc2[r2]+xn);
        hreg[r2] = fmaf(zv[r2], nv-hreg[r2], hreg[r2]);
        comb0[row*264+cX] = f2bf(hreg[r2]);
      }
      __syncthreads();                       // A: comb0(next h) ready
    }
    cur ^= 1;
  }
  #pragma unroll
  for(int r2=0;r2<4;r2++)
    out[(size_t)(b0 + q*4 + r2)*H_DIM + cX] = hreg[r2];
}

extern "C" void kernel_launch(void* const* d_in, const int* in_sizes, int n_in,
                              void* d_out, int out_size, void* d_ws, size_t ws_size,
                              hipStream_t stream) {
  const float* hs  = (const float*)d_in[0];
  const float* tgt = (const float*)d_in[1];
  const int*   len = (const int*)d_in[2];
  const float* W1  = (const float*)d_in[3];
  const float* b1  = (const float*)d_in[4];
  const float* W2  = (const float*)d_in[5];
  const float* Wr  = (const float*)d_in[6];
  const float* br  = (const float*)d_in[7];
  const float* Wz  = (const float*)d_in[8];
  const float* bz  = (const float*)d_in[9];
  const float* Wn  = (const float*)d_in[10];
  const float* bn  = (const float*)d_in[11];
  float* out = (float*)d_out;

  // ws layout (Round-3 verified): XPg (776-f16 planar) | wx | wrzh | wnh |
  // w1b | scores | att.  ws_size >= 422 MB proven by Rounds 3 & 5.
  const size_t XPG1_BYTES = (size_t)204800 * 776 * 2;   // 317,849,600
  short* xpgs = (short*)d_ws;
  short* wx   = (short*)((char*)d_ws + XPG1_BYTES);
  short* wrzh = wx + 196608;
  short* wnh  = wrzh + 131072;
  short* w1b  = wnh + 65536;
  float* scores = (float*)(w1b + 65536);
  float* att    = scores + (size_t)B_SZ*S_LEN;
  prep_kernel<<<1792, 256, 0, stream>>>(Wr, Wz, Wn, W1, wx, wrzh, wnh, w1b);
  xproj3_kernel<<<400, 1024, 0, stream>>>(hs, wx, br, bz, bn, xpgs);
  scores_kernel<<<800, 256, 0, stream>>>(hs, tgt, w1b, b1, W2, scores);
  softmax_kernel<<<1024, 256, 0, stream>>>(scores, len, att);
  scan2_kernel<<<64, 1024, 0, stream>>>(xpgs, att, wrzh, wnh, out);
}